// Round 1
// baseline (223.307 us; speedup 1.0000x reference)
//
#include <hip/hip_runtime.h>

// ---------------------------------------------------------------------------
// Problem constants
// ---------------------------------------------------------------------------
#define BATCH   16384
#define NF      16          // N_FEAT
#define OUTD    256         // OUT_DIM
#define NNEW    4828        // generated monomials (deg 2..4)
#define MTOT    4844        // 16 + 4828
#define KPAD    4864        // K padded to multiple of 32 (and 64)
#define KPAD2   (KPAD/2)    // 2432 u32 per row
#define ROWB    (KPAD*2)    // bytes per Epd row = 9728

// ---------------------------------------------------------------------------
// Compile-time expansion index table (replicates expansion_indices())
//   new term t: epd[16+t] = epd[J[t]] * epd[P[t]],  J<16, P<968
//   pass offsets: deg2 [0,136), deg3 [136,952), deg4 [952,4828)
// ---------------------------------------------------------------------------
struct ExpTab {
    unsigned int jp[NNEW];   // (J<<16) | P
    int off[4];
    int total;
};

constexpr ExpTab make_tab() {
    ExpTab t{};
    int Id[NF] = {};
    for (int i = 0; i < NF; ++i) Id[i] = i;
    int M = NF, idx = 0;
    for (int pass = 0; pass < 3; ++pass) {
        t.off[pass] = idx;
        const int hi = Id[NF - 1];          // Id[15] is only written at j=15, read-before-write
        for (int j = 0; j < NF; ++j) {
            const int lo = Id[j];
            for (int p = lo; p <= hi; ++p) t.jp[idx++] = ((unsigned)j << 16) | (unsigned)p;
            Id[j] = M;
            M += hi - lo + 1;
        }
    }
    t.off[3] = idx;
    t.total = M;
    return t;
}

constexpr ExpTab h_tab = make_tab();
static_assert(h_tab.off[1] == 136,  "deg2 count");
static_assert(h_tab.off[2] == 952,  "deg3 end");
static_assert(h_tab.off[3] == NNEW, "total new terms");
static_assert(h_tab.total  == MTOT, "M_TOTAL");

__device__ const ExpTab g_tab = make_tab();

// ---------------------------------------------------------------------------
// Helpers
// ---------------------------------------------------------------------------
__device__ inline unsigned bfpack2(float lo, float hi) {
    unsigned ul = __float_as_uint(lo), uh = __float_as_uint(hi);
    ul = (ul + 0x7fffu + ((ul >> 16) & 1u)) >> 16;          // RNE bf16, low half
    uh = (uh + 0x7fffu + ((uh >> 16) & 1u)) & 0xffff0000u;  // RNE bf16, high half
    return ul | uh;
}

__device__ inline void gld16(const void* g, void* l) {
    __builtin_amdgcn_global_load_lds(
        (const __attribute__((address_space(1))) unsigned int*)g,
        (__attribute__((address_space(3))) unsigned int*)l, 16, 0, 0);
}

typedef __attribute__((ext_vector_type(8))) short bf16x8;
typedef __attribute__((ext_vector_type(4))) float f32x4;

// ---------------------------------------------------------------------------
// Kernel 1: tanh + Taylor expansion -> Epd bf16 [rows][KPAD]
//   one wave per batch row; deg<=3 (968 terms) in LDS fp32, deg4 streamed out
// ---------------------------------------------------------------------------
__global__ __launch_bounds__(256) void expand_kernel(
    const float* __restrict__ x, unsigned* __restrict__ epd_u32)
{
    __shared__ float lds[4][968];
    const int w = threadIdx.x >> 6;
    const int l = threadIdx.x & 63;
    const size_t row = (size_t)blockIdx.x * 4 + w;
    float* my = lds[w];

    if (l < NF) my[l] = tanhf(x[row * NF + l]);
    __syncthreads();

    for (int t = l; t < 136; t += 64) {                  // degree 2
        unsigned jp = g_tab.jp[t];
        my[NF + t] = my[jp >> 16] * my[jp & 0xffffu];
    }
    __syncthreads();
    for (int t = 136 + l; t < 952; t += 64) {            // degree 3
        unsigned jp = g_tab.jp[t];
        my[NF + t] = my[jp >> 16] * my[jp & 0xffffu];
    }
    __syncthreads();

    unsigned* orow = epd_u32 + row * KPAD2;
    for (int i = l; i < 484; i += 64)                    // write deg<=3 (cols 0..967)
        orow[i] = bfpack2(my[2 * i], my[2 * i + 1]);
    for (int i = l; i < 1938; i += 64) {                 // degree 4, straight to global
        const int t = 952 + 2 * i;
        const unsigned jp0 = g_tab.jp[t], jp1 = g_tab.jp[t + 1];
        const float v0 = my[jp0 >> 16] * my[jp0 & 0xffffu];
        const float v1 = my[jp1 >> 16] * my[jp1 & 0xffffu];
        orow[484 + i] = bfpack2(v0, v1);
    }
    if (l < 10) orow[2422 + l] = 0u;                     // zero pad cols 4844..4863
}

// ---------------------------------------------------------------------------
// Kernel 2: W fp32 [256][4844] -> bf16 [256][KPAD] (zero-padded)
// ---------------------------------------------------------------------------
__global__ __launch_bounds__(256) void wconv_kernel(
    const float* __restrict__ W, unsigned* __restrict__ Wb)
{
    const int r = blockIdx.x;
    for (int i = threadIdx.x; i < KPAD2; i += 256) {
        const int c0 = 2 * i, c1 = 2 * i + 1;
        const float f0 = (c0 < MTOT) ? W[(size_t)r * MTOT + c0] : 0.f;
        const float f1 = (c1 < MTOT) ? W[(size_t)r * MTOT + c1] : 0.f;
        Wb[(size_t)r * KPAD2 + i] = bfpack2(f0, f1);
    }
}

// ---------------------------------------------------------------------------
// Kernel 3: C[rows][256] = relu(Epd[rows][KPAD] x Wb[256][KPAD]^T + bias)
//   BM=64 BN=256 BK=32, 512 threads (8 waves, 2x4), mfma_f32_16x16x32_bf16
// ---------------------------------------------------------------------------
__global__ __launch_bounds__(512, 2) void gemm_kernel(
    const unsigned short* __restrict__ A,   // [rows][KPAD] bf16
    const unsigned short* __restrict__ Bw,  // [256][KPAD] bf16
    const float* __restrict__ bias,
    float* __restrict__ C)
{
    __shared__ unsigned short As[64 * 32];    // [row][k]  4 KB
    __shared__ unsigned short Bs[256 * 32];   // [col][k] 16 KB
    const int t   = threadIdx.x;
    const int l   = t & 63;
    const int wid = t >> 6;
    const int wm  = wid >> 2;      // 0..1  (32-row band)
    const int wn  = wid & 3;       // 0..3  (64-col band)
    const int lr  = l & 15;        // fragment row/col
    const int lk  = l >> 4;        // k-chunk / acc row group
    const size_t m0 = (size_t)blockIdx.x * 64;

    f32x4 acc[2][4];
#pragma unroll
    for (int i = 0; i < 2; ++i)
#pragma unroll
        for (int j = 0; j < 4; ++j) acc[i][j] = (f32x4){0.f, 0.f, 0.f, 0.f};

    // staging: thread t covers 16B; A by waves 0..3, B by all 8 waves x2
    const unsigned short* gA  = A  + (m0 + (t >> 2)) * KPAD + (t & 3) * 8;
    const unsigned short* gB0 = Bw + (size_t)(t >> 2) * KPAD + (t & 3) * 8;
    const unsigned short* gB1 = Bw + (size_t)(128 + (t >> 2)) * KPAD + (t & 3) * 8;
    unsigned short* ldsA  = &As[wid * 512];          // wave-uniform bases
    unsigned short* ldsB0 = &Bs[wid * 512];
    unsigned short* ldsB1 = &Bs[4096 + wid * 512];

    for (int k0 = 0; k0 < KPAD; k0 += 32) {
        if (wid < 4) gld16(gA + k0, ldsA);
        gld16(gB0 + k0, ldsB0);
        gld16(gB1 + k0, ldsB1);
        __syncthreads();   // compiler drains vmcnt before s_barrier

        bf16x8 a[2], b[4];
#pragma unroll
        for (int mi = 0; mi < 2; ++mi)
            a[mi] = *(const bf16x8*)&As[(wm * 32 + mi * 16 + lr) * 32 + lk * 8];
#pragma unroll
        for (int ni = 0; ni < 4; ++ni)
            b[ni] = *(const bf16x8*)&Bs[(wn * 64 + ni * 16 + lr) * 32 + lk * 8];
#pragma unroll
        for (int mi = 0; mi < 2; ++mi)
#pragma unroll
            for (int ni = 0; ni < 4; ++ni)
                acc[mi][ni] = __builtin_amdgcn_mfma_f32_16x16x32_bf16(
                    a[mi], b[ni], acc[mi][ni], 0, 0, 0);
        __syncthreads();
    }

    // epilogue: D col = lane&15, row = (lane>>4)*4 + j   [m89 layout]
#pragma unroll
    for (int ni = 0; ni < 4; ++ni) {
        const int c = wn * 64 + ni * 16 + lr;
        const float bv = bias[c];
#pragma unroll
        for (int mi = 0; mi < 2; ++mi) {
            const size_t r = m0 + wm * 32 + mi * 16 + lk * 4;
#pragma unroll
            for (int j = 0; j < 4; ++j) {
                const float v = acc[mi][ni][j] + bv;
                C[(r + j) * OUTD + c] = fmaxf(v, 0.f);
            }
        }
    }
}

// ---------------------------------------------------------------------------
// Launch
// ---------------------------------------------------------------------------
extern "C" void kernel_launch(void* const* d_in, const int* in_sizes, int n_in,
                              void* d_out, int out_size, void* d_ws, size_t ws_size,
                              hipStream_t stream)
{
    const float* x    = (const float*)d_in[0];   // [16384,16,1]
    const float* W    = (const float*)d_in[1];   // [256,4844]
    const float* bias = (const float*)d_in[2];   // [256,1]
    float* out        = (float*)d_out;           // [16384,256,1]

    char* ws = (char*)d_ws;
    const size_t wb_bytes = (size_t)OUTD * KPAD2 * 4;    // 2,490,368 B
    unsigned* Wb = (unsigned*)ws;
    unsigned short* Epd = (unsigned short*)(ws + wb_bytes);

    // chunk batch rows so Epd fits in whatever workspace we got
    size_t avail = (ws_size > wb_bytes) ? ws_size - wb_bytes : 0;
    long long cap = (long long)(avail / ROWB);
    cap &= ~63LL;
    if (cap > BATCH) cap = BATCH;
    if (cap <= 0) cap = 64;   // assume ws is at least a few MB

    wconv_kernel<<<OUTD, 256, 0, stream>>>(W, Wb);
    for (long long r0 = 0; r0 < BATCH; r0 += cap) {
        const long long rows = (BATCH - r0 < cap) ? (BATCH - r0) : cap;
        expand_kernel<<<(int)(rows / 4), 256, 0, stream>>>(
            x + (size_t)r0 * NF, (unsigned*)Epd);
        gemm_kernel<<<(int)(rows / 64), 512, 0, stream>>>(
            (const unsigned short*)Epd, (const unsigned short*)Wb,
            bias, out + (size_t)r0 * OUTD);
    }
}